// Round 12
// baseline (3998.233 us; speedup 1.0000x reference)
//
#include <hip/hip_runtime.h>

typedef __bf16 bf16x8 __attribute__((ext_vector_type(8)));
typedef float f32x4 __attribute__((ext_vector_type(4)));
typedef unsigned short us;
typedef unsigned long long ull;

#define DEV static __device__ __forceinline__

DEV float bf2f(us u){ union { unsigned u; float f; } x; x.u = ((unsigned)u) << 16; return x.f; }
DEV us f2bf(float f){
  union { float f; unsigned u; } x; x.f = f;
  unsigned r = x.u + 0x7fffu + ((x.u >> 16) & 1u);
  return (us)(r >> 16);
}
DEV unsigned pack2(us lo, us hi){ return (unsigned)lo | ((unsigned)hi << 16); }
DEV float sigm(float x){ return 1.0f / (1.0f + expf(-x)); }
DEV float tanh_fast(float x){ float e = __expf(2.0f * x); return 1.0f - 2.0f / (e + 1.0f); }
DEV void unpk2(unsigned u, float& a, float& b){ a = bf2f((us)u); b = bf2f((us)(u >> 16)); }

// ---- coherent (agent-scope) accesses for cross-block mutable data ----
DEV unsigned ld4v(const unsigned* p){ return __hip_atomic_load(p, __ATOMIC_RELAXED, __HIP_MEMORY_SCOPE_AGENT); }
DEV ull ld8v(const void* p){ return __hip_atomic_load((const ull*)p, __ATOMIC_RELAXED, __HIP_MEMORY_SCOPE_AGENT); }
DEV void st4v(unsigned* p, unsigned v){ __hip_atomic_store(p, v, __ATOMIC_RELAXED, __HIP_MEMORY_SCOPE_AGENT); }

// ---- split-phase fence-free barriers ----
DEV void barS(unsigned* arr, unsigned ep){          // signal (after __syncthreads drains stores)
  __syncthreads();
  if (threadIdx.x == 0)
    __hip_atomic_store(arr + (size_t)blockIdx.x * 16, ep, __ATOMIC_RELEASE, __HIP_MEMORY_SCOPE_AGENT);
}
DEV void barW(unsigned* arr, unsigned ep){          // wait (128 blocks)
  if (threadIdx.x < 128){
    while (__hip_atomic_load(arr + (size_t)threadIdx.x * 16, __ATOMIC_RELAXED, __HIP_MEMORY_SCOPE_AGENT) < ep)
      __builtin_amdgcn_s_sleep(4);
  }
  __syncthreads();
}
DEV void gbarS(unsigned* gbase, int slot, unsigned ep){
  __syncthreads();
  if (threadIdx.x == 0)
    __hip_atomic_store(gbase + slot * 16, ep, __ATOMIC_RELEASE, __HIP_MEMORY_SCOPE_AGENT);
}
DEV void gbarW(unsigned* gbase, unsigned ep){
  if (threadIdx.x < 8){
    while (__hip_atomic_load(gbase + threadIdx.x * 16, __ATOMIC_RELAXED, __HIP_MEMORY_SCOPE_AGENT) < ep)
      __builtin_amdgcn_s_sleep(2);
  }
  __syncthreads();
}
DEV void gridbar3(unsigned* arr, unsigned ep){ barS(arr, ep); barW(arr, ep); }

// ---------------- f32 -> bf16 convert ----------------
__global__ void k_f2bf(const float4* __restrict__ in, uint2* __restrict__ out, long n4){
  long stride = (long)gridDim.x * blockDim.x;
  for (long i = (long)blockIdx.x * blockDim.x + threadIdx.x; i < n4; i += stride){
    float4 v = in[i];
    uint2 o; o.x = pack2(f2bf(v.x), f2bf(v.y)); o.y = pack2(f2bf(v.z), f2bf(v.w));
    out[i] = o;
  }
}

__global__ void k_bias3(const float* a0, const float* b0, float* o0,
                        const float* a1, const float* b1, float* o1,
                        const float* a2, const float* b2, float* o2){
  int i = blockIdx.x * 256 + threadIdx.x;   // 2048
  o0[i] = a0[i] + b0[i];
  o1[i] = a1[i] + b1[i];
  o2[i] = a2[i] + b2[i];
}

// embedding gather -> bf16 rows. row r = pos*16 + b
__global__ void k_embed(const int* __restrict__ tok, const float* __restrict__ table,
                        us* __restrict__ out){
  int r = blockIdx.x;
  int b = r & 15, pos = r >> 4;
  int idx = tok[b * 128 + pos];
  float4 v = ((const float4*)(table + (size_t)idx * 512))[threadIdx.x];  // 128 threads
  uint2 o; o.x = pack2(f2bf(v.x), f2bf(v.y)); o.y = pack2(f2bf(v.z), f2bf(v.w));
  ((uint2*)(out + (size_t)r * 512))[threadIdx.x] = o;
}

// ---------------- bf16 MFMA GEMM: C[M,N] = A[M,K] * B[N,K]^T (+bias) ----------------
template<int MODE>
__global__ __launch_bounds__(256)
void gemm_bt(const us* __restrict__ A, int lda,
             const us* __restrict__ B, int ldb,
             const float* __restrict__ bias,
             void* __restrict__ Cv, int ldc, int K, int mvalid)
{
  __shared__ __align__(16) us As[128 * 64];
  __shared__ __align__(16) us Bs[128 * 64];
  const int tid  = threadIdx.x;
  const int lane = tid & 63, wid = tid >> 6;
  const int wm = (wid >> 1) * 64, wn = (wid & 1) * 64;
  const us* Ab = A + (size_t)blockIdx.y * 128 * lda;
  const us* Bb = B + (size_t)blockIdx.x * 128 * ldb;

  f32x4 acc[4][4] = {};
  bf16x8 ga[4], gb[4];

  #pragma unroll
  for (int r = 0; r < 4; r++){
    int c = tid + r * 256;
    ga[r] = *(const bf16x8*)(Ab + (size_t)(c >> 3) * lda + (c & 7) * 8);
    gb[r] = *(const bf16x8*)(Bb + (size_t)(c >> 3) * ldb + (c & 7) * 8);
  }
  const int nt = K >> 6;
  for (int t = 0; t < nt; t++){
    #pragma unroll
    for (int r = 0; r < 4; r++){
      int c = tid + r * 256;
      int slot = ((c >> 3) * 8 + ((c & 7) ^ ((c >> 3) & 7))) * 8;
      *(bf16x8*)(As + slot) = ga[r];
      *(bf16x8*)(Bs + slot) = gb[r];
    }
    __syncthreads();
    if (t + 1 < nt){
      int k0 = (t + 1) * 64;
      #pragma unroll
      for (int r = 0; r < 4; r++){
        int c = tid + r * 256;
        ga[r] = *(const bf16x8*)(Ab + (size_t)(c >> 3) * lda + k0 + (c & 7) * 8);
        gb[r] = *(const bf16x8*)(Bb + (size_t)(c >> 3) * ldb + k0 + (c & 7) * 8);
      }
    }
    #pragma unroll
    for (int kk = 0; kk < 2; kk++){
      bf16x8 av[4], bv[4];
      #pragma unroll
      for (int i = 0; i < 4; i++){
        int ra = wm + i * 16 + (lane & 15);
        int ua = (kk * 4 + (lane >> 4)) ^ (ra & 7);
        av[i] = *(const bf16x8*)(As + (ra * 8 + ua) * 8);
        int rb = wn + i * 16 + (lane & 15);
        int ub = (kk * 4 + (lane >> 4)) ^ (rb & 7);
        bv[i] = *(const bf16x8*)(Bs + (rb * 8 + ub) * 8);
      }
      #pragma unroll
      for (int i = 0; i < 4; i++)
        #pragma unroll
        for (int j = 0; j < 4; j++)
          acc[i][j] = __builtin_amdgcn_mfma_f32_16x16x32_bf16(av[i], bv[j], acc[i][j], 0, 0, 0);
    }
    if (t + 1 < nt) __syncthreads();
  }

  const int cb = lane & 15, rb4 = (lane >> 4) * 4;
  #pragma unroll
  for (int i = 0; i < 4; i++){
    #pragma unroll
    for (int j = 0; j < 4; j++){
      #pragma unroll
      for (int r = 0; r < 4; r++){
        int row = blockIdx.y * 128 + wm + i * 16 + rb4 + r;
        int col = blockIdx.x * 128 + wn + j * 16 + cb;
        float v = acc[i][j][r];
        if (bias) v += bias[col];
        if (MODE == 0) ((float*)Cv)[(size_t)row * ldc + col] = v;
        else           ((us*)Cv)[(size_t)row * ldc + col] = f2bf(v);
      }
    }
  }
}

// ---------------- M precompute: M[n][b][s] = Wc[n]·eo[b][s]  (bf16 out) ----------------
// grid (1, 16, 16): by = n-tile, bz = batch. A = wihd+512 (lda 1536), B = eo[b] (ldb 1024), K=1024.
__global__ __launch_bounds__(256)
void gemm_M(const us* __restrict__ A, const us* __restrict__ B0, us* __restrict__ M)
{
  __shared__ __align__(16) us As[128 * 64];
  __shared__ __align__(16) us Bs[128 * 64];
  const int tid  = threadIdx.x;
  const int lane = tid & 63, wid = tid >> 6;
  const int wm = (wid >> 1) * 64, wn = (wid & 1) * 64;
  const us* Ab = A + (size_t)blockIdx.y * 128 * 1536;
  const us* Bb = B0 + (size_t)blockIdx.z * 131072;

  f32x4 acc[4][4] = {};
  bf16x8 ga[4], gb[4];
  #pragma unroll
  for (int r = 0; r < 4; r++){
    int c = tid + r * 256;
    ga[r] = *(const bf16x8*)(Ab + (size_t)(c >> 3) * 1536 + (c & 7) * 8);
    gb[r] = *(const bf16x8*)(Bb + (size_t)(c >> 3) * 1024 + (c & 7) * 8);
  }
  for (int t = 0; t < 16; t++){
    #pragma unroll
    for (int r = 0; r < 4; r++){
      int c = tid + r * 256;
      int slot = ((c >> 3) * 8 + ((c & 7) ^ ((c >> 3) & 7))) * 8;
      *(bf16x8*)(As + slot) = ga[r];
      *(bf16x8*)(Bs + slot) = gb[r];
    }
    __syncthreads();
    if (t + 1 < 16){
      int k0 = (t + 1) * 64;
      #pragma unroll
      for (int r = 0; r < 4; r++){
        int c = tid + r * 256;
        ga[r] = *(const bf16x8*)(Ab + (size_t)(c >> 3) * 1536 + k0 + (c & 7) * 8);
        gb[r] = *(const bf16x8*)(Bb + (size_t)(c >> 3) * 1024 + k0 + (c & 7) * 8);
      }
    }
    #pragma unroll
    for (int kk = 0; kk < 2; kk++){
      bf16x8 av[4], bv[4];
      #pragma unroll
      for (int i = 0; i < 4; i++){
        int ra = wm + i * 16 + (lane & 15);
        int ua = (kk * 4 + (lane >> 4)) ^ (ra & 7);
        av[i] = *(const bf16x8*)(As + (ra * 8 + ua) * 8);
        int rb = wn + i * 16 + (lane & 15);
        int ub = (kk * 4 + (lane >> 4)) ^ (rb & 7);
        bv[i] = *(const bf16x8*)(Bs + (rb * 8 + ub) * 8);
      }
      #pragma unroll
      for (int i = 0; i < 4; i++)
        #pragma unroll
        for (int j = 0; j < 4; j++)
          acc[i][j] = __builtin_amdgcn_mfma_f32_16x16x32_bf16(av[i], bv[j], acc[i][j], 0, 0, 0);
    }
    if (t + 1 < 16) __syncthreads();
  }
  const int cb = lane & 15, rb4 = (lane >> 4) * 4;
  #pragma unroll
  for (int i = 0; i < 4; i++)
    #pragma unroll
    for (int j = 0; j < 4; j++)
      #pragma unroll
      for (int r = 0; r < 4; r++){
        int row = blockIdx.y * 128 + wm + i * 16 + rb4 + r;   // n
        int col = wn + j * 16 + cb;                            // s
        M[(size_t)row * 2048 + blockIdx.z * 128 + col] = f2bf(acc[i][j][r]);
      }
}

// =================================================================================
// Persistent encoder v4 (unchanged)
// =================================================================================
__global__ __launch_bounds__(256)
void enc_persist4(const float* __restrict__ gin_f, const float* __restrict__ gin_b,
                  const us* __restrict__ whhf_bf, const us* __restrict__ whhb_bf,
                  us* __restrict__ enc_out_bf, /* [16][128][1024] bf16 */
                  unsigned* __restrict__ arr)
{
  __shared__ __align__(16) us Wt[2][1024][8];
  __shared__ __align__(16) us Hrow[2][16][520];
  __shared__ __align__(16) f32x4 P[2][4][64];
  __shared__ float gl[2][16][17];
  __shared__ float hvout[2][16][4];

  const int bx = blockIdx.x, tid = threadIdx.x;
  const int lane = tid & 63, wv = tid >> 6;

  for (int d = 0; d < 2; d++){
    const us* srcw = d ? whhb_bf : whhf_bf;
    for (int u = tid; u < 1024; u += 256){
      int ks = u >> 6, ch = (u >> 4) & 3, v = u & 15;
      int n = (v & 3) * 512 + bx * 4 + (v >> 2);
      *(bf16x8*)Wt[d][u] = *(const bf16x8*)(srcw + (size_t)n * 512 + ks * 32 + ch * 8);
    }
  }

  float creg = 0.0f;
  const int cd = (tid >> 6) & 1, cb = tid & 15, cj = (tid >> 4) & 3;

  for (int t = 0; t < 128; t++){
    if (t == 0){
      #pragma unroll
      for (int r = 0; r < 8; r++){
        int u = tid + r * 256;
        int d = u >> 10, b = (u >> 6) & 15, s16 = u & 63;
        *(ull*)&Hrow[d][b][s16 * 8]     = 0ull;
        *(ull*)&Hrow[d][b][s16 * 8 + 4] = 0ull;
      }
    } else {
      #pragma unroll
      for (int r = 0; r < 8; r++){
        int u = tid + r * 256;
        int d = u >> 10, b = (u >> 6) & 15, s16 = u & 63;
        int sp = d ? (128 - t) : (t - 1);
        const us* s = enc_out_bf + ((size_t)b * 128 + sp) * 1024 + d * 512 + s16 * 8;
        ull lo = ld8v(s), hi = ld8v(s + 4);
        *(ull*)&Hrow[d][b][s16 * 8]     = lo;
        *(ull*)&Hrow[d][b][s16 * 8 + 4] = hi;
      }
    }
    __syncthreads();
    #pragma unroll
    for (int d = 0; d < 2; d++){
      f32x4 acc = {};
      #pragma unroll
      for (int m = 0; m < 4; m++){
        int ks = wv * 4 + m;
        int ch = lane >> 4, b = lane & 15;
        acc = __builtin_amdgcn_mfma_f32_16x16x32_bf16(*(const bf16x8*)&Hrow[d][b][ks * 32 + ch * 8],
                                                      *(const bf16x8*)Wt[d][(ks * 4 + ch) * 16 + b],
                                                      acc, 0, 0, 0);
      }
      P[d][wv][lane] = acc;
    }
    __syncthreads();
    if (wv < 2){
      int d = wv;
      f32x4 sum = (P[d][0][lane] + P[d][1][lane]) + (P[d][2][lane] + P[d][3][lane]);
      int v = lane & 15;
      int n = (v & 3) * 512 + bx * 4 + (v >> 2);
      int s_in = d ? (127 - t) : t;
      const float* gg = (d ? gin_b : gin_f) + (size_t)s_in * 16 * 2048 + n;
      #pragma unroll
      for (int r = 0; r < 4; r++){
        int b = (lane >> 4) * 4 + r;
        gl[d][v][b] = sum[r] + gg[(size_t)b * 2048];
      }
    }
    __syncthreads();
    if (tid < 128){
      float ig = sigm (gl[cd][cj * 4 + 0][cb]);
      float fg = sigm (gl[cd][cj * 4 + 1][cb]);
      float g2 = tanhf(gl[cd][cj * 4 + 2][cb]);
      float og = sigm (gl[cd][cj * 4 + 3][cb]);
      float cn = fg * creg + ig * g2;
      float hv = og * tanhf(cn);
      creg = cn;
      hvout[cd][cb][cj] = hv;
    }
    __syncthreads();
    if (tid < 64){
      int d = tid >> 5, rem = tid & 31, b = rem & 15, jp = rem >> 4;
      int s_in = d ? (127 - t) : t;
      st4v((unsigned*)(enc_out_bf + ((size_t)b * 128 + s_in) * 1024 + d * 512 + bx * 4 + jp * 2),
           pack2(f2bf(hvout[d][b][jp * 2]), f2bf(hvout[d][b][jp * 2 + 1])));
    }
    if (t != 127) gridbar3(arr, t + 1);
  }
}

// ---------------- h0/c0 ----------------
__global__ __launch_bounds__(512)
void k_h0c0(const us* __restrict__ enc_out_bf, const float* __restrict__ Wbh, const float* __restrict__ bbh,
            const float* __restrict__ Wbc, const float* __restrict__ bbc,
            us* __restrict__ h0_bf, float* __restrict__ c_dec)
{
  __shared__ float hc[1024];
  int b = blockIdx.x >> 1, which = blockIdx.x & 1;
  int tid = threadIdx.x;
  hc[tid]       = bf2f(enc_out_bf[((size_t)b * 128 + 127) * 1024 + tid]);
  hc[512 + tid] = bf2f(enc_out_bf[((size_t)b * 128 + 0)   * 1024 + 512 + tid]);
  __syncthreads();
  const float* W = which ? Wbc : Wbh;
  float acc = (which ? bbc : bbh)[tid];
  const float* wr = W + (size_t)tid * 1024;
  for (int k = 0; k < 1024; k += 4){
    float4 w = *(const float4*)(wr + k);
    acc += w.x * hc[k] + w.y * hc[k + 1] + w.z * hc[k + 2] + w.w * hc[k + 3];
  }
  float v = tanhf(acc);
  if (which) c_dec[b * 512 + tid] = v;
  else       h0_bf[b * 512 + tid] = f2bf(v);
}

// =================================================================================
// Fused decoder v9 + streaming logits GEMM.
//  blocks 0..127  : decoder; per step: group(pscore, MFMA hidden) -> global(att, ctx
//                   hidden) -> gates via precomputed M -> global(h).
//  blocks 128..255: logits GEMM consumers (BM=256), Wfc via nontemporal loads.
// =================================================================================
#define SMEM_BYTES 121856

__global__ __launch_bounds__(256)
void dec_fused4(const us* __restrict__ h0_bf, const float* __restrict__ c_dec0,
                const float* __restrict__ Ws_att, const float* __restrict__ v_att,
                const us* __restrict__ enc_proj_bf, const us* __restrict__ enc_out_bf,
                const int* __restrict__ src_lens, const float* __restrict__ gin_d,
                const us* __restrict__ whhd_bf, const us* __restrict__ Mmat,
                float* __restrict__ pscore_g, float* __restrict__ att_g,
                us* __restrict__ hctx,
                const us* __restrict__ wfc, const float* __restrict__ bfc,
                float* __restrict__ out,
                unsigned* __restrict__ arr, unsigned* __restrict__ arrG,
                unsigned* __restrict__ tdone)
{
  __shared__ __align__(16) char smem[SMEM_BYTES];
  const int tid = threadIdx.x;

  if (blockIdx.x >= 128){
    // ------------- consumer: logits GEMM, BM=256 x BN=128, NT Wfc loads -------------
    us* As = (us*)smem;            // 256x64 = 32KB
    us* Bs = (us*)(smem + 32768);  // 128x64 = 16KB
    const int lane = tid & 63, wid = tid >> 6;
    const int wm = wid * 64;
    for (int tile = blockIdx.x - 128; tile < 2000; tile += 128){
      int rt = tile / 250, ct = tile - rt * 250;
      unsigned need = (rt == 7) ? 127u : (unsigned)(16 * rt + 16);
      if (tid == 0){
        while (ld4v(tdone) < need) __builtin_amdgcn_s_sleep(8);
      }
      __syncthreads();
      const us* Ab = hctx + (size_t)rt * 256 * 1536;
      const us* Bb = wfc  + (size_t)ct * 128 * 1536;
      f32x4 acc[4][8] = {};
      bf16x8 ga[8], gb[4];
      #pragma unroll
      for (int r = 0; r < 8; r++){
        int cc = tid + r * 256;
        int row = cc >> 3, piece = cc & 7;
        bool val = (rt * 256 + row) < 2032;
        union { ull q[2]; bf16x8 v; } u;
        const us* p = Ab + (size_t)row * 1536 + piece * 8;
        u.q[0] = val ? ld8v(p) : 0ull;
        u.q[1] = val ? ld8v(p + 4) : 0ull;
        ga[r] = u.v;
      }
      #pragma unroll
      for (int r = 0; r < 4; r++){
        int cc = tid + r * 256;
        gb[r] = __builtin_nontemporal_load((const bf16x8*)(Bb + (size_t)(cc >> 3) * 1536 + (cc & 7) * 8));
      }
      for (int tk = 0; tk < 24; tk++){
        #pragma unroll
        for (int r = 0; r < 8; r++){
          int cc = tid + r * 256;
          int slot = ((cc >> 3) * 8 + ((cc & 7) ^ ((cc >> 3) & 7))) * 8;
          *(bf16x8*)(As + slot) = ga[r];
        }
        #pragma unroll
        for (int r = 0; r < 4; r++){
          int cc = tid + r * 256;
          int slot = ((cc >> 3) * 8 + ((cc & 7) ^ ((cc >> 3) & 7))) * 8;
          *(bf16x8*)(Bs + slot) = gb[r];
        }
        __syncthreads();
        if (tk + 1 < 24){
          int k0 = (tk + 1) * 64;
          #pragma unroll
          for (int r = 0; r < 8; r++){
            int cc = tid + r * 256;
            int row = cc >> 3, piece = cc & 7;
            bool val = (rt * 256 + row) < 2032;
            union { ull q[2]; bf16x8 v; } u;
            const us* p = Ab + (size_t)row * 1536 + k0 + piece * 8;
            u.q[0] = val ? ld8v(p) : 0ull;
            u.q[1] = val ? ld8v(p + 4) : 0ull;
            ga[r] = u.v;
          }
          #pragma unroll
          for (int r = 0; r < 4; r++){
            int cc = tid + r * 256;
            gb[r] = __builtin_nontemporal_load((const bf16x8*)(Bb + (size_t)(cc >> 3) * 1536 + k0 + (cc & 7) * 8));
          }
        }
        #pragma unroll
        for (int kk = 0; kk < 2; kk++){
          bf16x8 av[4], bv[8];
          #pragma unroll
          for (int i = 0; i < 4; i++){
            int ra = wm + i * 16 + (lane & 15);
            int ua = (kk * 4 + (lane >> 4)) ^ (ra & 7);
            av[i] = *(const bf16x8*)(As + (ra * 8 + ua) * 8);
          }
          #pragma unroll
          for (int j = 0; j < 8; j++){
            int rb = j * 16 + (lane & 15);
            int ub = (kk * 4 + (lane >> 4)) ^ (rb & 7);
            bv[j] = *(const bf16x8*)(Bs + (rb * 8 + ub) * 8);
          }
          #pragma unroll
          for (int i = 0; i < 4; i++)
            #pragma unroll
            for (int j = 0; j < 8; j++)
              acc[i][j] = __builtin_amdgcn_mfma_f32_16x16x32_bf16(av[i], bv[j], acc[i][j], 0, 0, 0);
        }
        if (tk + 1 < 24) __syncthreads();
      }
      const int cbl = lane & 15, rb4 = (lane >> 4) * 4;
      #pragma unroll
      for (int i = 0; i < 4; i++){
        #pragma unroll
        for (int j = 0; j < 8; j++){
          #pragma unroll
          for (int r = 0; r < 4; r++){
            int row = rt * 256 + wm + i * 16 + rb4 + r;
            int col = ct * 128 + j * 16 + cbl;
            if (row < 2032){
              float v = acc[i][j][r] + bfc[col];
              int tt = row >> 4, b = row & 15;
              out[((size_t)b * 127 + tt) * 32000 + col] = v;
            }
          }
        }
      }
    }
    return;
  }

  // ---------------- producer: decoder v9 ----------------
  us (*Wh)[8]      = (us(*)[8])(smem);                     // 16KB
  us (*Ws64)[520]  = (us(*)[520])(smem + 16384);           // 65KB
  us (*Xrow)[520]  = (us(*)[520])(smem + 82944);           // 16.6KB (h staging)
  f32x4 (*P)[64]   = (f32x4(*)[64])(smem + 99584);         // 4KB
  float (*g1l)[17] = (float(*)[17])(smem + 103680);
  float (*gl)[17]  = (float(*)[17])(smem + 104768);
  float* vl64      = (float*)(smem + 105856);              // 256B
  float (*hsp)[64] = (float(*)[64])(smem + 106112);        // 1KB
  float* hs_own    = (float*)(smem + 107136);              // 256B
  float (*pall)[128] = (float(*)[128])(smem + 107392);     // 4KB
  float* e_own     = (float*)(smem + 111488);              // 512B
  float (*e_sm)[132] = (float(*)[132])(smem + 112000);     // 8.4KB
  float* inv_sm    = (float*)(smem + 120448);              // 64B
  float (*cred)[128] = (float(*)[128])(smem + 120512);     // 1KB  (also dred alias)
  float* sred      = (float*)(smem + 121536);              // 32B
  float (*hvs)[4]  = (float(*)[4])(smem + 121568);         // 256B

  const int bx = blockIdx.x;
  const int lane = tid & 63, wv = tid >> 6;
  const int bB = bx & 15, sQ = bx >> 4;
  unsigned* gbase = arrG + bB * 128;

  // ---- resident loads (once) ----
  for (int u = tid; u < 1024; u += 256){
    int ks = u >> 6, ch = (u >> 4) & 3, v = u & 15;
    int n = (v & 3) * 512 + bx * 4 + (v >> 2);
    *(bf16x8*)Wh[u] = *(const bf16x8*)(whhd_bf + (size_t)n * 512 + ks * 32 + ch * 8);
  }
  for (int u = tid; u < 32768; u += 256){      // Ws rows sQ*64 .. +63
    int a = u >> 9, k = u & 511;
    Ws64[a][k] = f2bf(Ws_att[(size_t)(sQ * 64 + a) * 512 + k]);
  }
  if (tid < 64) vl64[tid] = v_att[sQ * 64 + tid];
  const int slen = src_lens[bB];

  // own n-rows of M (base pointer per thread-v)
  const int vIdx = tid >> 4, bIdx = tid & 15;
  const int nOwn = (vIdx & 3) * 512 + bx * 4 + (vIdx >> 2);
  const us* Mrow = Mmat + (size_t)nOwn * 2048 + bIdx * 128;

  float creg = 0.0f;
  if (tid < 64) creg = c_dec0[(tid & 15) * 512 + bx * 4 + (tid >> 4)];

  for (int t = 0; t < 127; t++){
    const us* hsrc = t ? (hctx + (size_t)(t - 1) * 16 * 1536) : h0_bf;
    const int hstride = t ? 1536 : 512;

    // ====== phase A: stage h; hs partials; pscore; SIGNAL group; MFMA overlap ======
    #pragma unroll
    for (int r = 0; r < 4; r++){
      int u = tid + r * 256;
      int b = u >> 6, s16 = u & 63;
      const us* s = hsrc + (size_t)b * hstride + s16 * 8;
      ull lo = ld8v(s), hi = ld8v(s + 4);
      *(ull*)&Xrow[b][s16 * 8]     = lo;
      *(ull*)&Xrow[b][s16 * 8 + 4] = hi;
    }
    __syncthreads();
    {  // hs partials for own batch: wave wv = k-quarter, lane = a' (0..63)
      const us* wr = Ws64[lane] + wv * 128;
      const us* xr = Xrow[bB] + wv * 128;
      float s = 0.f;
      #pragma unroll
      for (int k = 0; k < 128; k += 8){
        bf16x8 xv = *(const bf16x8*)(xr + k);
        bf16x8 wv8 = *(const bf16x8*)(wr + k);
        #pragma unroll
        for (int e = 0; e < 8; e++) s += (float)xv[e] * (float)wv8[e];
      }
      hsp[wv][lane] = s;
    }
    __syncthreads();
    if (tid < 64) hs_own[tid] = hsp[0][tid] + hsp[1][tid] + hsp[2][tid] + hsp[3][tid];
    __syncthreads();
    {  // partial scores over own a-slice: s = tid>>1, a-half = tid&1
      int s = tid >> 1, half = tid & 1;
      const us* er = enc_proj_bf + ((size_t)bB * 128 + s) * 512 + sQ * 64 + half * 32;
      const float* hb = hs_own + half * 32;
      const float* vp = vl64 + half * 32;
      float sv = 0.f;
      #pragma unroll
      for (int a = 0; a < 32; a += 8){
        uint4 u4 = *(const uint4*)(er + a);
        float e0,e1,e2,e3,e4,e5,e6,e7;
        unpk2(u4.x,e0,e1); unpk2(u4.y,e2,e3); unpk2(u4.z,e4,e5); unpk2(u4.w,e6,e7);
        sv += vp[a+0]*tanh_fast(e0+hb[a+0]) + vp[a+1]*tanh_fast(e1+hb[a+1])
            + vp[a+2]*tanh_fast(e2+hb[a+2]) + vp[a+3]*tanh_fast(e3+hb[a+3])
            + vp[a+4]*tanh_fast(e4+hb[a+4]) + vp[a+5]*tanh_fast(e5+hb[a+5])
            + vp[a+6]*tanh_fast(e6+hb[a+6]) + vp[a+7]*tanh_fast(e7+hb[a+7]);
      }
      sv += __shfl_xor(sv, 1);
      if (half == 0)
        st4v((unsigned*)&pscore_g[(size_t)bB * 1024 + sQ * 128 + s], __float_as_uint(sv));
    }
    gbarS(gbase, sQ, t + 1);

    // overlap: h@Whh MFMA + g1l (hidden under group leg)
    {
      f32x4 acc = {};
      #pragma unroll
      for (int m = 0; m < 4; m++){
        int ks = wv * 4 + m;
        int ch = lane >> 4, b = lane & 15;
        acc = __builtin_amdgcn_mfma_f32_16x16x32_bf16(*(const bf16x8*)&Xrow[b][ks * 32 + ch * 8],
                                                      *(const bf16x8*)Wh[(ks * 4 + ch) * 16 + b],
                                                      acc, 0, 0, 0);
      }
      P[wv][lane] = acc;
    }
    __syncthreads();
    if (wv == 0){
      f32x4 sum = (P[0][lane] + P[1][lane]) + (P[2][lane] + P[3][lane]);
      int v = lane & 15;
      int n = (v & 3) * 512 + bx * 4 + (v >> 2);
      #pragma unroll
      for (int r = 0; r < 4; r++){
        int b = (lane >> 4) * 4 + r;
        g1l[v][b] = sum[r] + gin_d[((size_t)t * 16 + b) * 2048 + n];
      }
    }
    gbarW(gbase, t + 1);

    // ====== phase B: e = exp(sum partials), publish slice; SIGNAL att; ctx overlap ======
    for (int u = tid; u < 1024; u += 256)
      (&pall[0][0])[u] = __uint_as_float(ld4v((unsigned*)&pscore_g[(size_t)bB * 1024 + u]));
    __syncthreads();
    {
      float e = 0.f;
      if (tid < 128){
        float sc = ((pall[0][tid] + pall[1][tid]) + (pall[2][tid] + pall[3][tid]))
                 + ((pall[4][tid] + pall[5][tid]) + (pall[6][tid] + pall[7][tid]));
        e = (tid < slen) ? __expf(sc) : 0.f;
        e_own[tid] = e;
        if ((tid >> 4) == sQ)
          st4v((unsigned*)&att_g[bB * 128 + tid], __float_as_uint(e));
      }
      float ss = e;
      #pragma unroll
      for (int o = 32; o; o >>= 1) ss += __shfl_xor(ss, o);
      if (lane == 0 && wv < 2) sred[wv] = ss;   // tid<128 covers wv 0,1
    }
    barS(arr, 2 * t + 1);

    // overlap: ctx[bB][sQ*128..+127] (hidden under att leg)
    {
      int kk = tid & 127, half = tid >> 7;
      const float* ab = e_own + half * 64;
      const us* er = enc_out_bf + ((size_t)(bB * 128 + half * 64)) * 1024 + sQ * 128 + kk;
      float s = 0.f;
      #pragma unroll 8
      for (int s2 = 0; s2 < 64; s2++)
        s += ab[s2] * bf2f(er[(size_t)s2 * 1024]);
      cred[half][kk] = s;
    }
    __syncthreads();
    if (tid < 64){
      float inv = 1.0f / (sred[0] + sred[1]);
      int kk2 = tid * 2;
      float c0 = (cred[0][kk2]     + cred[1][kk2])     * inv;
      float c1 = (cred[0][kk2 + 1] + cred[1][kk2 + 1]) * inv;
      st4v((unsigned*)(hctx + ((size_t)t * 16 + bB) * 1536 + 512 + sQ * 128 + kk2),
           pack2(f2bf(c0), f2bf(c1)));
    }
    barW(arr, 2 * t + 1);

    // ====== phase C: gates via M; cell; publish h; SIGNAL/WAIT h leg ======
    for (int u = tid; u < 2048; u += 256){
      int b = u >> 7, s = u & 127;
      e_sm[b][s] = __uint_as_float(ld4v((unsigned*)&att_g[b * 128 + s]));
    }
    __syncthreads();
    {  // denominators
      float* dred = &cred[0][0];   // [16][8] alias
      if (tid < 128){
        int b = tid >> 3, oct = tid & 7;
        float s = 0.f;
        #pragma unroll
        for (int i = 0; i < 16; i++) s += e_sm[b][oct * 16 + i];
        dred[b * 8 + oct] = s;
      }
      __syncthreads();
      if (tid < 16){
        float s = 0.f;
        #pragma unroll
        for (int i = 0; i < 8; i++) s += dred[tid * 8 + i];
        inv_sm[tid] = 1.0f / s;
      }
    }
    __syncthreads();
    {  // g2[n][b] = (sum_s e[b][s] * M[n][b][s]) * inv[b] + g1l
      float acc = 0.f;
      const float* eb = e_sm[bIdx];
      #pragma unroll
      for (int s8 = 0; s8 < 16; s8++){
        bf16x8 m = *(const bf16x8*)(Mrow + s8 * 8);
        #pragma unroll
        for (int e = 0; e < 8; e++)
          acc += eb[s8 * 8 + e] * (float)m[e];
      }
      gl[vIdx][bIdx] = acc * inv_sm[bIdx] + g1l[vIdx][bIdx];
    }
    __syncthreads();
    if (tid < 64){
      int b2 = tid & 15, joff = tid >> 4;
      float ig = sigm (gl[joff * 4 + 0][b2]);
      float fg = sigm (gl[joff * 4 + 1][b2]);
      float g2 = tanhf(gl[joff * 4 + 2][b2]);
      float og = sigm (gl[joff * 4 + 3][b2]);
      float cn = fg * creg + ig * g2;
      float hv = og * tanhf(cn);
      creg = cn;
      hvs[b2][joff] = hv;
    }
    __syncthreads();
    if (tid < 32){
      int b = tid & 15, jp = tid >> 4;
      st4v((unsigned*)(hctx + ((size_t)t * 16 + b) * 1536 + bx * 4 + jp * 2),
           pack2(f2bf(hvs[b][jp * 2]), f2bf(hvs[b][jp * 2 + 1])));
    }
    barS(arr, 2 * t + 2);
    barW(arr, 2 * t + 2);
    if (bx == 0 && tid == 0)
      __hip_atomic_store(tdone, (unsigned)(t + 1), __ATOMIC_RELEASE, __HIP_MEMORY_SCOPE_AGENT);
  }
}

extern "C" void kernel_launch(void* const* d_in, const int* in_sizes, int n_in,
                              void* d_out, int out_size, void* d_ws, size_t ws_size,
                              hipStream_t stream)
{
  const int*   src       = (const int*)d_in[0];
  const int*   src_lens  = (const int*)d_in[1];
  const int*   tgt       = (const int*)d_in[2];
  const float* enc_embed = (const float*)d_in[3];
  const float* Wih_f = (const float*)d_in[4];
  const float* Whh_f = (const float*)d_in[5];
  const float* bih_f = (const float*)d_in[6];
  const float* bhh_f = (const float*)d_in[7];
  const float* Wih_b = (const float*)d_in[8];
  const float* Whh_b = (const float*)d_in[9];
  const float* bih_b = (const float*)d_in[10];
  const float* bhh_b = (const float*)d_in[11];
  const float* Wbh = (const float*)d_in[12];
  const float* bbh = (const float*)d_in[13];
  const float* Wbc = (const float*)d_in[14];
  const float* bbc = (const float*)d_in[15];
  const float* Wh_att = (const float*)d_in[16];
  const float* Ws_att = (const float*)d_in[17];
  const float* v_att  = (const float*)d_in[18];
  const float* dec_embed = (const float*)d_in[19];
  const float* Wih_d = (const float*)d_in[20];
  const float* Whh_d = (const float*)d_in[21];
  const float* bih_d = (const float*)d_in[22];
  const float* bhh_d = (const float*)d_in[23];
  const float* Wfc = (const float*)d_in[24];
  const float* bfc = (const float*)d_in[25];
  float* out = (float*)d_out;

  char* base = (char*)d_ws;
  size_t off = 0;
  auto take = [&](size_t bytes) -> char* {
    char* p = base + off;
    off += (bytes + 255) & ~(size_t)255;
    return p;
  };
  us* wfc_bf    = (us*)take((size_t)32000 * 1536 * 2);
  us* emb_e     = (us*)take((size_t)2048 * 512 * 2);
  us* emb_d     = (us*)take((size_t)2048 * 512 * 2);
  us* wihf_bf   = (us*)take((size_t)2048 * 512 * 2);
  us* wihb_bf   = (us*)take((size_t)2048 * 512 * 2);
  us* wihd_bf   = (us*)take((size_t)2048 * 1536 * 2);
  us* whhf_bf   = (us*)take((size_t)2048 * 512 * 2);
  us* whhb_bf   = (us*)take((size_t)2048 * 512 * 2);
  us* whhd_bf   = (us*)take((size_t)2048 * 512 * 2);
  us* whatt_bf  = (us*)take((size_t)512 * 1024 * 2);
  us* Mmat      = (us*)take((size_t)2048 * 16 * 128 * 2);
  float* gin_f    = (float*)take((size_t)2048 * 2048 * 4);
  float* gin_b    = (float*)take((size_t)2048 * 2048 * 4);
  float* gin_d    = (float*)take((size_t)2048 * 2048 * 4);
  us* enc_out_bf  = (us*)take((size_t)2048 * 1024 * 2);
  us* enc_proj_bf = (us*)take((size_t)2048 * 512 * 2);
  us* hctx        = (us*)take((size_t)2048 * 1536 * 2);
  us* h0_bf       = (us*)take((size_t)16 * 512 * 2);
  float* c_dec    = (float*)take((size_t)16 * 512 * 4);
  float* pscore_g = (float*)take((size_t)16 * 1024 * 4);
  float* att_g    = (float*)take((size_t)16 * 128 * 4);
  float* bias_f = (float*)take(2048 * 4);
  float* bias_b = (float*)take(2048 * 4);
  float* bias_d = (float*)take(2048 * 4);
  unsigned* arrE  = (unsigned*)take(128 * 16 * 4);
  unsigned* arrD  = (unsigned*)take(128 * 16 * 4);
  unsigned* arrG  = (unsigned*)take(16 * 8 * 16 * 4);
  unsigned* tdone = (unsigned*)take(256);

  // zeroing: padded dec-embedding rows, hctx, barrier flags + t_done
  hipMemsetAsync(emb_d, 0, (size_t)2048 * 512 * 2, stream);
  hipMemsetAsync(hctx, 0, (size_t)2048 * 1536 * 2, stream);
  hipMemsetAsync(arrE, 0, (128 * 16 + 128 * 16 + 16 * 8 * 16) * 4 + 256, stream);

  // weight conversions
  k_f2bf<<<4096, 256, 0, stream>>>((const float4*)Wfc,   (uint2*)wfc_bf,   (long)32000 * 1536 / 4);
  k_f2bf<<<512,  256, 0, stream>>>((const float4*)Wih_f, (uint2*)wihf_bf,  (long)2048 * 512 / 4);
  k_f2bf<<<512,  256, 0, stream>>>((const float4*)Wih_b, (uint2*)wihb_bf,  (long)2048 * 512 / 4);
  k_f2bf<<<1024, 256, 0, stream>>>((const float4*)Wih_d, (uint2*)wihd_bf,  (long)2048 * 1536 / 4);
  k_f2bf<<<512,  256, 0, stream>>>((const float4*)Whh_f, (uint2*)whhf_bf,  (long)2048 * 512 / 4);
  k_f2bf<<<512,  256, 0, stream>>>((const float4*)Whh_b, (uint2*)whhb_bf,  (long)2048 * 512 / 4);
  k_f2bf<<<512,  256, 0, stream>>>((const float4*)Whh_d, (uint2*)whhd_bf,  (long)2048 * 512 / 4);
  k_f2bf<<<512,  256, 0, stream>>>((const float4*)Wh_att,(uint2*)whatt_bf, (long)512 * 1024 / 4);
  k_bias3<<<8, 256, 0, stream>>>(bih_f, bhh_f, bias_f, bih_b, bhh_b, bias_b, bih_d, bhh_d, bias_d);

  // embeddings (bf16), rows r = pos*16 + b
  k_embed<<<2048, 128, 0, stream>>>(src, enc_embed, emb_e);
  k_embed<<<2032, 128, 0, stream>>>(tgt, dec_embed, emb_d);

  // input-side gate GEMMs (hoisted out of the scans)
  gemm_bt<0><<<dim3(16, 16), 256, 0, stream>>>(emb_e, 512, wihf_bf, 512,  bias_f, gin_f, 2048, 512, 4096);
  gemm_bt<0><<<dim3(16, 16), 256, 0, stream>>>(emb_e, 512, wihb_bf, 512,  bias_b, gin_b, 2048, 512, 4096);
  gemm_bt<0><<<dim3(16, 16), 256, 0, stream>>>(emb_d, 512, wihd_bf, 1536, bias_d, gin_d, 2048, 512, 4096);

  // encoder: persistent, fence-free barriers
  enc_persist4<<<128, 256, 0, stream>>>(gin_f, gin_b, whhf_bf, whhb_bf, enc_out_bf, arrE);

  k_h0c0<<<32, 512, 0, stream>>>(enc_out_bf, Wbh, bbh, Wbc, bbc, h0_bf, c_dec);

  // enc_proj (bf16) = enc_out @ Wh_att^T
  gemm_bt<2><<<dim3(4, 16), 256, 0, stream>>>(enc_out_bf, 1024, whatt_bf, 1024, nullptr, enc_proj_bf, 512, 1024, 4096);

  // M[n][b][s] = Wc[n] · eo[b][s]  (one-time batched GEMM)
  gemm_M<<<dim3(1, 16, 16), 256, 0, stream>>>(wihd_bf + 512, enc_out_bf, Mmat);

  // fused decoder v9 + streaming logits GEMM (128 producers + 128 consumers)
  dec_fused4<<<256, 256, 0, stream>>>(h0_bf, c_dec, Ws_att, v_att, enc_proj_bf, enc_out_bf, src_lens,
                                      gin_d, whhd_bf, Mmat, pscore_g, att_g, hctx,
                                      wfc_bf, bfc, out, arrD, arrG, tdone);
}

// Round 13
// 3165.787 us; speedup vs baseline: 1.2630x; 1.2630x over previous
//
#include <hip/hip_runtime.h>

typedef __bf16 bf16x8 __attribute__((ext_vector_type(8)));
typedef float f32x4 __attribute__((ext_vector_type(4)));
typedef unsigned short us;
typedef unsigned long long ull;

#define DEV static __device__ __forceinline__

DEV float bf2f(us u){ union { unsigned u; float f; } x; x.u = ((unsigned)u) << 16; return x.f; }
DEV us f2bf(float f){
  union { float f; unsigned u; } x; x.f = f;
  unsigned r = x.u + 0x7fffu + ((x.u >> 16) & 1u);
  return (us)(r >> 16);
}
DEV unsigned pack2(us lo, us hi){ return (unsigned)lo | ((unsigned)hi << 16); }
DEV float sigm(float x){ return 1.0f / (1.0f + expf(-x)); }
DEV float tanh_fast(float x){ float e = __expf(2.0f * x); return 1.0f - 2.0f / (e + 1.0f); }
DEV void unpk2(unsigned u, float& a, float& b){ a = bf2f((us)u); b = bf2f((us)(u >> 16)); }

// ---- coherent (agent-scope) accesses for cross-block mutable data ----
DEV unsigned ld4v(const unsigned* p){ return __hip_atomic_load(p, __ATOMIC_RELAXED, __HIP_MEMORY_SCOPE_AGENT); }
DEV ull ld8v(const void* p){ return __hip_atomic_load((const ull*)p, __ATOMIC_RELAXED, __HIP_MEMORY_SCOPE_AGENT); }
DEV void st4v(unsigned* p, unsigned v){ __hip_atomic_store(p, v, __ATOMIC_RELAXED, __HIP_MEMORY_SCOPE_AGENT); }

// ---- fence-free barriers ----
DEV void barS(unsigned* arr, unsigned ep){
  __syncthreads();
  if (threadIdx.x == 0)
    __hip_atomic_store(arr + (size_t)blockIdx.x * 16, ep, __ATOMIC_RELEASE, __HIP_MEMORY_SCOPE_AGENT);
}
DEV void barW(unsigned* arr, unsigned ep){
  if (threadIdx.x < 128){
    while (__hip_atomic_load(arr + (size_t)threadIdx.x * 16, __ATOMIC_RELAXED, __HIP_MEMORY_SCOPE_AGENT) < ep)
      __builtin_amdgcn_s_sleep(4);
  }
  __syncthreads();
}
DEV void gridbar3(unsigned* arr, unsigned ep){ barS(arr, ep); barW(arr, ep); }

DEV void gbarS(unsigned* gbase, int slot, unsigned ep){
  __syncthreads();
  if (threadIdx.x == 0)
    __hip_atomic_store(gbase + slot * 16, ep, __ATOMIC_RELEASE, __HIP_MEMORY_SCOPE_AGENT);
}
DEV void gbarW(unsigned* gbase, unsigned ep){
  if (threadIdx.x < 8){
    while (__hip_atomic_load(gbase + threadIdx.x * 16, __ATOMIC_RELAXED, __HIP_MEMORY_SCOPE_AGENT) < ep)
      __builtin_amdgcn_s_sleep(2);
  }
  __syncthreads();
}

// 64-block barrier (encoder per-direction domain)
DEV void encbar64(unsigned* arr, int bl, unsigned ep){
  __syncthreads();
  if (threadIdx.x == 0)
    __hip_atomic_store(arr + (size_t)bl * 16, ep, __ATOMIC_RELEASE, __HIP_MEMORY_SCOPE_AGENT);
  if (threadIdx.x < 64){
    while (__hip_atomic_load(arr + (size_t)threadIdx.x * 16, __ATOMIC_RELAXED, __HIP_MEMORY_SCOPE_AGENT) < ep)
      __builtin_amdgcn_s_sleep(4);
  }
  __syncthreads();
}

// ---------------- f32 -> bf16 convert ----------------
__global__ void k_f2bf(const float4* __restrict__ in, uint2* __restrict__ out, long n4){
  long stride = (long)gridDim.x * blockDim.x;
  for (long i = (long)blockIdx.x * blockDim.x + threadIdx.x; i < n4; i += stride){
    float4 v = in[i];
    uint2 o; o.x = pack2(f2bf(v.x), f2bf(v.y)); o.y = pack2(f2bf(v.z), f2bf(v.w));
    out[i] = o;
  }
}

__global__ void k_bias3(const float* a0, const float* b0, float* o0,
                        const float* a1, const float* b1, float* o1,
                        const float* a2, const float* b2, float* o2){
  int i = blockIdx.x * 256 + threadIdx.x;   // 2048
  o0[i] = a0[i] + b0[i];
  o1[i] = a1[i] + b1[i];
  o2[i] = a2[i] + b2[i];
}

// embedding gather -> bf16 rows. row r = pos*16 + b
__global__ void k_embed(const int* __restrict__ tok, const float* __restrict__ table,
                        us* __restrict__ out){
  int r = blockIdx.x;
  int b = r & 15, pos = r >> 4;
  int idx = tok[b * 128 + pos];
  float4 v = ((const float4*)(table + (size_t)idx * 512))[threadIdx.x];  // 128 threads
  uint2 o; o.x = pack2(f2bf(v.x), f2bf(v.y)); o.y = pack2(f2bf(v.z), f2bf(v.w));
  ((uint2*)(out + (size_t)r * 512))[threadIdx.x] = o;
}

// ---------------- bf16 MFMA GEMM: C[M,N] = A[M,K] * B[N,K]^T (+bias) ----------------
template<int MODE>
__global__ __launch_bounds__(256)
void gemm_bt(const us* __restrict__ A, int lda,
             const us* __restrict__ B, int ldb,
             const float* __restrict__ bias,
             void* __restrict__ Cv, int ldc, int K, int mvalid)
{
  __shared__ __align__(16) us As[128 * 64];
  __shared__ __align__(16) us Bs[128 * 64];
  const int tid  = threadIdx.x;
  const int lane = tid & 63, wid = tid >> 6;
  const int wm = (wid >> 1) * 64, wn = (wid & 1) * 64;
  const us* Ab = A + (size_t)blockIdx.y * 128 * lda;
  const us* Bb = B + (size_t)blockIdx.x * 128 * ldb;

  f32x4 acc[4][4] = {};
  bf16x8 ga[4], gb[4];

  #pragma unroll
  for (int r = 0; r < 4; r++){
    int c = tid + r * 256;
    ga[r] = *(const bf16x8*)(Ab + (size_t)(c >> 3) * lda + (c & 7) * 8);
    gb[r] = *(const bf16x8*)(Bb + (size_t)(c >> 3) * ldb + (c & 7) * 8);
  }
  const int nt = K >> 6;
  for (int t = 0; t < nt; t++){
    #pragma unroll
    for (int r = 0; r < 4; r++){
      int c = tid + r * 256;
      int slot = ((c >> 3) * 8 + ((c & 7) ^ ((c >> 3) & 7))) * 8;
      *(bf16x8*)(As + slot) = ga[r];
      *(bf16x8*)(Bs + slot) = gb[r];
    }
    __syncthreads();
    if (t + 1 < nt){
      int k0 = (t + 1) * 64;
      #pragma unroll
      for (int r = 0; r < 4; r++){
        int c = tid + r * 256;
        ga[r] = *(const bf16x8*)(Ab + (size_t)(c >> 3) * lda + k0 + (c & 7) * 8);
        gb[r] = *(const bf16x8*)(Bb + (size_t)(c >> 3) * ldb + k0 + (c & 7) * 8);
      }
    }
    #pragma unroll
    for (int kk = 0; kk < 2; kk++){
      bf16x8 av[4], bv[4];
      #pragma unroll
      for (int i = 0; i < 4; i++){
        int ra = wm + i * 16 + (lane & 15);
        int ua = (kk * 4 + (lane >> 4)) ^ (ra & 7);
        av[i] = *(const bf16x8*)(As + (ra * 8 + ua) * 8);
        int rb = wn + i * 16 + (lane & 15);
        int ub = (kk * 4 + (lane >> 4)) ^ (rb & 7);
        bv[i] = *(const bf16x8*)(Bs + (rb * 8 + ub) * 8);
      }
      #pragma unroll
      for (int i = 0; i < 4; i++)
        #pragma unroll
        for (int j = 0; j < 4; j++)
          acc[i][j] = __builtin_amdgcn_mfma_f32_16x16x32_bf16(av[i], bv[j], acc[i][j], 0, 0, 0);
    }
    if (t + 1 < nt) __syncthreads();
  }

  const int cb = lane & 15, rb4 = (lane >> 4) * 4;
  #pragma unroll
  for (int i = 0; i < 4; i++){
    #pragma unroll
    for (int j = 0; j < 4; j++){
      #pragma unroll
      for (int r = 0; r < 4; r++){
        int row = blockIdx.y * 128 + wm + i * 16 + rb4 + r;
        int col = blockIdx.x * 128 + wn + j * 16 + cb;
        float v = acc[i][j][r];
        if (bias) v += bias[col];
        if (MODE == 0) ((float*)Cv)[(size_t)row * ldc + col] = v;
        else           ((us*)Cv)[(size_t)row * ldc + col] = f2bf(v);
      }
    }
  }
}

// =================================================================================
// Persistent encoder v5: fwd (blocks 0..63) and bwd (64..127) in INDEPENDENT
// 64-block barrier domains. Each block owns 8 j of its direction.
// =================================================================================
__global__ __launch_bounds__(256)
void enc_persist5(const float* __restrict__ gin_f, const float* __restrict__ gin_b,
                  const us* __restrict__ whhf_bf, const us* __restrict__ whhb_bf,
                  us* __restrict__ enc_out_bf, /* [16][128][1024] bf16 */
                  unsigned* __restrict__ arrF, unsigned* __restrict__ arrB)
{
  __shared__ __align__(16) us Wt[2][1024][8];   // 32KB: two 4-j subtiles
  __shared__ __align__(16) us Hrow[16][520];    // own-dir h, padded row-major
  __shared__ __align__(16) f32x4 P[2][4][64];
  __shared__ float gl[2][16][17];
  __shared__ float hvout[16][8];

  const int bx = blockIdx.x, tid = threadIdx.x;
  const int lane = tid & 63, wv = tid >> 6;
  const int dir = bx >> 6, bl = bx & 63;
  unsigned* arr = dir ? arrB : arrF;
  const us* whh = dir ? whhb_bf : whhf_bf;
  const float* gin = dir ? gin_b : gin_f;

  for (int ti = 0; ti < 2; ti++)
    for (int u = tid; u < 1024; u += 256){
      int ks = u >> 6, ch = (u >> 4) & 3, v = u & 15;
      int n = (v & 3) * 512 + bl * 8 + ti * 4 + (v >> 2);
      *(bf16x8*)Wt[ti][u] = *(const bf16x8*)(whh + (size_t)n * 512 + ks * 32 + ch * 8);
    }

  float creg = 0.0f;
  const int cb = tid & 15, cjo = (tid >> 4) & 7;   // cell owner: tid<128

  for (int t = 0; t < 128; t++){
    if (t == 0){
      #pragma unroll
      for (int r = 0; r < 4; r++){
        int u = tid + r * 256;
        int b = u >> 6, s16 = u & 63;
        *(ull*)&Hrow[b][s16 * 8]     = 0ull;
        *(ull*)&Hrow[b][s16 * 8 + 4] = 0ull;
      }
    } else {
      int sp = dir ? (128 - t) : (t - 1);
      #pragma unroll
      for (int r = 0; r < 4; r++){
        int u = tid + r * 256;
        int b = u >> 6, s16 = u & 63;
        const us* s = enc_out_bf + ((size_t)b * 128 + sp) * 1024 + dir * 512 + s16 * 8;
        ull lo = ld8v(s), hi = ld8v(s + 4);
        *(ull*)&Hrow[b][s16 * 8]     = lo;
        *(ull*)&Hrow[b][s16 * 8 + 4] = hi;
      }
    }
    __syncthreads();
    #pragma unroll
    for (int ti = 0; ti < 2; ti++){
      f32x4 acc = {};
      #pragma unroll
      for (int m = 0; m < 4; m++){
        int ks = wv * 4 + m;
        int ch = lane >> 4, b = lane & 15;
        acc = __builtin_amdgcn_mfma_f32_16x16x32_bf16(*(const bf16x8*)&Hrow[b][ks * 32 + ch * 8],
                                                      *(const bf16x8*)Wt[ti][(ks * 4 + ch) * 16 + b],
                                                      acc, 0, 0, 0);
      }
      P[ti][wv][lane] = acc;
    }
    __syncthreads();
    if (wv < 2){
      int ti = wv;
      f32x4 sum = (P[ti][0][lane] + P[ti][1][lane]) + (P[ti][2][lane] + P[ti][3][lane]);
      int v = lane & 15;
      int n = (v & 3) * 512 + bl * 8 + ti * 4 + (v >> 2);
      int s_in = dir ? (127 - t) : t;
      const float* gg = gin + (size_t)s_in * 16 * 2048 + n;
      #pragma unroll
      for (int r = 0; r < 4; r++){
        int b = (lane >> 4) * 4 + r;
        gl[ti][v][b] = sum[r] + gg[(size_t)b * 2048];
      }
    }
    __syncthreads();
    if (tid < 128){
      int ti = cjo >> 2, jr = cjo & 3;
      float ig = sigm (gl[ti][jr * 4 + 0][cb]);
      float fg = sigm (gl[ti][jr * 4 + 1][cb]);
      float g2 = tanhf(gl[ti][jr * 4 + 2][cb]);
      float og = sigm (gl[ti][jr * 4 + 3][cb]);
      float cn = fg * creg + ig * g2;
      float hv = og * tanhf(cn);
      creg = cn;
      hvout[cb][cjo] = hv;
    }
    __syncthreads();
    if (tid < 64){
      int b = tid & 15, jp = tid >> 4;   // jp 0..3 -> j-pairs
      int s_in = dir ? (127 - t) : t;
      st4v((unsigned*)(enc_out_bf + ((size_t)b * 128 + s_in) * 1024 + dir * 512 + bl * 8 + jp * 2),
           pack2(f2bf(hvout[b][jp * 2]), f2bf(hvout[b][jp * 2 + 1])));
    }
    if (t != 127) encbar64(arr, bl, t + 1);
  }
}

// ---------------- h0/c0 ----------------
__global__ __launch_bounds__(512)
void k_h0c0(const us* __restrict__ enc_out_bf, const float* __restrict__ Wbh, const float* __restrict__ bbh,
            const float* __restrict__ Wbc, const float* __restrict__ bbc,
            us* __restrict__ h0_bf, float* __restrict__ c_dec)
{
  __shared__ float hc[1024];
  int b = blockIdx.x >> 1, which = blockIdx.x & 1;
  int tid = threadIdx.x;
  hc[tid]       = bf2f(enc_out_bf[((size_t)b * 128 + 127) * 1024 + tid]);
  hc[512 + tid] = bf2f(enc_out_bf[((size_t)b * 128 + 0)   * 1024 + 512 + tid]);
  __syncthreads();
  const float* W = which ? Wbc : Wbh;
  float acc = (which ? bbc : bbh)[tid];
  const float* wr = W + (size_t)tid * 1024;
  for (int k = 0; k < 1024; k += 4){
    float4 w = *(const float4*)(wr + k);
    acc += w.x * hc[k] + w.y * hc[k + 1] + w.z * hc[k + 2] + w.w * hc[k + 3];
  }
  float v = tanhf(acc);
  if (which) c_dec[b * 512 + tid] = v;
  else       h0_bf[b * 512 + tid] = f2bf(v);
}

// =================================================================================
// Fused decoder v10 + streaming logits GEMM.
//  blocks 0..127  : decoder; group leg (MFMA hidden) + 2 global legs per step.
//                   Phase B ctx via vectorized bf16x8 eo reads + LDS reduce.
//  blocks 128..255: logits GEMM consumers (BM=256), Wfc via nontemporal loads.
// =================================================================================
#define SMEM_BYTES 161440

__global__ __launch_bounds__(256)
void dec_fused5(const us* __restrict__ h0_bf, const float* __restrict__ c_dec0,
                const float* __restrict__ Ws_att, const float* __restrict__ v_att,
                const us* __restrict__ enc_proj_bf, const us* __restrict__ enc_out_bf,
                const int* __restrict__ src_lens, const float* __restrict__ gin_d,
                const us* __restrict__ whhd_bf, const us* __restrict__ wihd_bf,
                float* __restrict__ pscore_g,
                us* __restrict__ hctx,
                const us* __restrict__ wfc, const float* __restrict__ bfc,
                float* __restrict__ out,
                unsigned* __restrict__ arr, unsigned* __restrict__ arrG,
                unsigned* __restrict__ tdone)
{
  __shared__ __align__(16) char smem[SMEM_BYTES];
  const int tid = threadIdx.x;

  if (blockIdx.x >= 128){
    // ------------- consumer: logits GEMM, BM=256 x BN=128, NT Wfc loads -------------
    us* As = (us*)smem;            // 256x64 = 32KB
    us* Bs = (us*)(smem + 32768);  // 128x64 = 16KB
    const int lane = tid & 63, wid = tid >> 6;
    const int wm = wid * 64;
    for (int tile = blockIdx.x - 128; tile < 2000; tile += 128){
      int rt = tile / 250, ct = tile - rt * 250;
      unsigned need = (rt == 7) ? 127u : (unsigned)(16 * rt + 16);
      if (tid == 0){
        while (ld4v(tdone) < need) __builtin_amdgcn_s_sleep(8);
      }
      __syncthreads();
      const us* Ab = hctx + (size_t)rt * 256 * 1536;
      const us* Bb = wfc  + (size_t)ct * 128 * 1536;
      f32x4 acc[4][8] = {};
      bf16x8 ga[8], gb[4];
      #pragma unroll
      for (int r = 0; r < 8; r++){
        int cc = tid + r * 256;
        int row = cc >> 3, piece = cc & 7;
        bool val = (rt * 256 + row) < 2032;
        union { ull q[2]; bf16x8 v; } u;
        const us* p = Ab + (size_t)row * 1536 + piece * 8;
        u.q[0] = val ? ld8v(p) : 0ull;
        u.q[1] = val ? ld8v(p + 4) : 0ull;
        ga[r] = u.v;
      }
      #pragma unroll
      for (int r = 0; r < 4; r++){
        int cc = tid + r * 256;
        gb[r] = __builtin_nontemporal_load((const bf16x8*)(Bb + (size_t)(cc >> 3) * 1536 + (cc & 7) * 8));
      }
      for (int tk = 0; tk < 24; tk++){
        #pragma unroll
        for (int r = 0; r < 8; r++){
          int cc = tid + r * 256;
          int slot = ((cc >> 3) * 8 + ((cc & 7) ^ ((cc >> 3) & 7))) * 8;
          *(bf16x8*)(As + slot) = ga[r];
        }
        #pragma unroll
        for (int r = 0; r < 4; r++){
          int cc = tid + r * 256;
          int slot = ((cc >> 3) * 8 + ((cc & 7) ^ ((cc >> 3) & 7))) * 8;
          *(bf16x8*)(Bs + slot) = gb[r];
        }
        __syncthreads();
        if (tk + 1 < 24){
          int k0 = (tk + 1) * 64;
          #pragma unroll
          for (int r = 0; r < 8; r++){
            int cc = tid + r * 256;
            int row = cc >> 3, piece = cc & 7;
            bool val = (rt * 256 + row) < 2032;
            union { ull q[2]; bf16x8 v; } u;
            const us* p = Ab + (size_t)row * 1536 + k0 + piece * 8;
            u.q[0] = val ? ld8v(p) : 0ull;
            u.q[1] = val ? ld8v(p + 4) : 0ull;
            ga[r] = u.v;
          }
          #pragma unroll
          for (int r = 0; r < 4; r++){
            int cc = tid + r * 256;
            gb[r] = __builtin_nontemporal_load((const bf16x8*)(Bb + (size_t)(cc >> 3) * 1536 + k0 + (cc & 7) * 8));
          }
        }
        #pragma unroll
        for (int kk = 0; kk < 2; kk++){
          bf16x8 av[4], bv[8];
          #pragma unroll
          for (int i = 0; i < 4; i++){
            int ra = wm + i * 16 + (lane & 15);
            int ua = (kk * 4 + (lane >> 4)) ^ (ra & 7);
            av[i] = *(const bf16x8*)(As + (ra * 8 + ua) * 8);
          }
          #pragma unroll
          for (int j = 0; j < 8; j++){
            int rb = j * 16 + (lane & 15);
            int ub = (kk * 4 + (lane >> 4)) ^ (rb & 7);
            bv[j] = *(const bf16x8*)(Bs + (rb * 8 + ub) * 8);
          }
          #pragma unroll
          for (int i = 0; i < 4; i++)
            #pragma unroll
            for (int j = 0; j < 8; j++)
              acc[i][j] = __builtin_amdgcn_mfma_f32_16x16x32_bf16(av[i], bv[j], acc[i][j], 0, 0, 0);
        }
        if (tk + 1 < 24) __syncthreads();
      }
      const int cbl = lane & 15, rb4 = (lane >> 4) * 4;
      #pragma unroll
      for (int i = 0; i < 4; i++){
        #pragma unroll
        for (int j = 0; j < 8; j++){
          #pragma unroll
          for (int r = 0; r < 4; r++){
            int row = rt * 256 + wm + i * 16 + rb4 + r;
            int col = ct * 128 + j * 16 + cbl;
            if (row < 2032){
              float v = acc[i][j][r] + bfc[col];
              int tt = row >> 4, b = row & 15;
              out[((size_t)b * 127 + tt) * 32000 + col] = v;
            }
          }
        }
      }
    }
    return;
  }

  // ---------------- producer: decoder v10 ----------------
  us (*Wh)[8]      = (us(*)[8])(smem);                     // 16KB
  us (*Wc)[8]      = (us(*)[8])(smem + 16384);             // 32KB -> 49152
  us (*Ws64)[520]  = (us(*)[520])(smem + 49152);           // 65KB -> 115712
  us (*Xrow)[1032] = (us(*)[1032])(smem + 115712);         // 33KB -> 148736
  float (*credv)[132] = (float(*)[132])(smem + 115712);    // alias (phase B only)
  f32x4 (*P)[64]   = (f32x4(*)[64])(smem + 148736);        // 4KB -> 152832
  float (*g1l)[17] = (float(*)[17])(smem + 152832);        // -> 153920
  float (*gl)[17]  = (float(*)[17])(smem + 153920);        // -> 155008
  float* vl64      = (float*)(smem + 155008);              // -> 155264
  float (*hsp)[64] = (float(*)[64])(smem + 155264);        // -> 156288
  float* hs_own    = (float*)(smem + 156288);              // -> 156544
  float (*pall)[128] = (float(*)[128])(smem + 156544);     // -> 160640
  float* e_own     = (float*)(smem + 160640);              // -> 161152
  float* sred      = (float*)(smem + 161152);              // -> 161184
  float (*hvs)[4]  = (float(*)[4])(smem + 161184);         // -> 161440

  const int bx = blockIdx.x;
  const int lane = tid & 63, wv = tid >> 6;
  const int bB = bx & 15, sQ = bx >> 4;
  unsigned* gbase = arrG + bB * 128;

  // ---- resident loads (once) ----
  for (int u = tid; u < 1024; u += 256){
    int ks = u >> 6, ch = (u >> 4) & 3, v = u & 15;
    int n = (v & 3) * 512 + bx * 4 + (v >> 2);
    *(bf16x8*)Wh[u] = *(const bf16x8*)(whhd_bf + (size_t)n * 512 + ks * 32 + ch * 8);
  }
  for (int u = tid; u < 2048; u += 256){
    int ks = u >> 6, ch = (u >> 4) & 3, v = u & 15;
    int n = (v & 3) * 512 + bx * 4 + (v >> 2);
    *(bf16x8*)Wc[u] = *(const bf16x8*)(wihd_bf + (size_t)n * 1536 + 512 + ks * 32 + ch * 8);
  }
  for (int u = tid; u < 32768; u += 256){      // Ws rows sQ*64 .. +63
    int a = u >> 9, k = u & 511;
    Ws64[a][k] = f2bf(Ws_att[(size_t)(sQ * 64 + a) * 512 + k]);
  }
  if (tid < 64) vl64[tid] = v_att[sQ * 64 + tid];
  const int slen = src_lens[bB];

  float creg = 0.0f;                 // tid<64 owns (b=tid&15, j=bx*4+(tid>>4))
  if (tid < 64) creg = c_dec0[(tid & 15) * 512 + bx * 4 + (tid >> 4)];

  for (int t = 0; t < 127; t++){
    const us* hsrc = t ? (hctx + (size_t)(t - 1) * 16 * 1536) : h0_bf;
    const int hstride = t ? 1536 : 512;

    // ====== phase A: stage h; hs partials; pscore; group-SIGNAL; MFMA overlap ======
    #pragma unroll
    for (int r = 0; r < 4; r++){
      int u = tid + r * 256;
      int b = u >> 6, s16 = u & 63;
      const us* s = hsrc + (size_t)b * hstride + s16 * 8;
      ull lo = ld8v(s), hi = ld8v(s + 4);
      *(ull*)&Xrow[b][s16 * 8]     = lo;
      *(ull*)&Xrow[b][s16 * 8 + 4] = hi;
    }
    __syncthreads();
    {  // hs partials for own batch: wave wv = k-quarter, lane = a' (0..63)
      const us* wr = Ws64[lane] + wv * 128;
      const us* xr = Xrow[bB] + wv * 128;
      float s = 0.f;
      #pragma unroll
      for (int k = 0; k < 128; k += 8){
        bf16x8 xv = *(const bf16x8*)(xr + k);
        bf16x8 wv8 = *(const bf16x8*)(wr + k);
        #pragma unroll
        for (int e = 0; e < 8; e++) s += (float)xv[e] * (float)wv8[e];
      }
      hsp[wv][lane] = s;
    }
    __syncthreads();
    if (tid < 64) hs_own[tid] = hsp[0][tid] + hsp[1][tid] + hsp[2][tid] + hsp[3][tid];
    __syncthreads();
    {  // partial scores over own a-slice: s = tid>>1, a-half = tid&1
      int s = tid >> 1, half = tid & 1;
      const us* er = enc_proj_bf + ((size_t)bB * 128 + s) * 512 + sQ * 64 + half * 32;
      const float* hb = hs_own + half * 32;
      const float* vp = vl64 + half * 32;
      float sv = 0.f;
      #pragma unroll
      for (int a = 0; a < 32; a += 8){
        uint4 u4 = *(const uint4*)(er + a);
        float e0,e1,e2,e3,e4,e5,e6,e7;
        unpk2(u4.x,e0,e1); unpk2(u4.y,e2,e3); unpk2(u4.z,e4,e5); unpk2(u4.w,e6,e7);
        sv += vp[a+0]*tanh_fast(e0+hb[a+0]) + vp[a+1]*tanh_fast(e1+hb[a+1])
            + vp[a+2]*tanh_fast(e2+hb[a+2]) + vp[a+3]*tanh_fast(e3+hb[a+3])
            + vp[a+4]*tanh_fast(e4+hb[a+4]) + vp[a+5]*tanh_fast(e5+hb[a+5])
            + vp[a+6]*tanh_fast(e6+hb[a+6]) + vp[a+7]*tanh_fast(e7+hb[a+7]);
      }
      sv += __shfl_xor(sv, 1);
      if (half == 0)
        st4v((unsigned*)&pscore_g[(size_t)bB * 1024 + sQ * 128 + s], __float_as_uint(sv));
    }
    gbarS(gbase, sQ, t + 1);

    // overlap: h@Whh MFMA + g1l (hidden under group leg)
    {
      f32x4 acc = {};
      #pragma unroll
      for (int m = 0; m < 4; m++){
        int ks = wv * 4 + m;
        int ch = lane >> 4, b = lane & 15;
        acc = __builtin_amdgcn_mfma_f32_16x16x32_bf16(*(const bf16x8*)&Xrow[b][ks * 32 + ch * 8],
                                                      *(const bf16x8*)Wh[(ks * 4 + ch) * 16 + b],
                                                      acc, 0, 0, 0);
      }
      P[wv][lane] = acc;
    }
    __syncthreads();
    if (wv == 0){
      f32x4 sum = (P[0][lane] + P[1][lane]) + (P[2][lane] + P[3][lane]);
      int v = lane & 15;
      int n = (v & 3) * 512 + bx * 4 + (v >> 2);
      #pragma unroll
      for (int r = 0; r < 4; r++){
        int b = (lane >> 4) * 4 + r;
        g1l[v][b] = sum[r] + gin_d[((size_t)t * 16 + b) * 2048 + n];
      }
    }
    gbarW(gbase, t + 1);

    // ====== phase B: e = exp(sum partials); vectorized ctx; publish ======
    for (int u = tid; u < 512; u += 256)
      ((ull*)&pall[0][0])[u] = ld8v(&pscore_g[(size_t)bB * 1024 + u * 2]);
    __syncthreads();
    {
      float e = 0.f;
      if (tid < 128){
        float sc = ((pall[0][tid] + pall[1][tid]) + (pall[2][tid] + pall[3][tid]))
                 + ((pall[4][tid] + pall[5][tid]) + (pall[6][tid] + pall[7][tid]));
        e = (tid < slen) ? __expf(sc) : 0.f;
        e_own[tid] = e;
      }
      float ss = e;
      #pragma unroll
      for (int o = 32; o; o >>= 1) ss += __shfl_xor(ss, o);
      if (lane == 0) sred[wv] = ss;
    }
    __syncthreads();
    {  // ctx partials: sg = tid>>4 (8 s each), kb = tid&15 (8 k each), bf16x8 eo reads
      int sg = tid >> 4, kb = tid & 15;
      const us* base = enc_out_bf + ((size_t)(bB * 128 + sg * 8)) * 1024 + sQ * 128 + kb * 8;
      f32x4 a0 = {}, a1 = {};
      #pragma unroll
      for (int si = 0; si < 8; si++){
        bf16x8 v = *(const bf16x8*)(base + (size_t)si * 1024);
        float ev = e_own[sg * 8 + si];
        a0[0] += ev * (float)v[0]; a0[1] += ev * (float)v[1];
        a0[2] += ev * (float)v[2]; a0[3] += ev * (float)v[3];
        a1[0] += ev * (float)v[4]; a1[1] += ev * (float)v[5];
        a1[2] += ev * (float)v[6]; a1[3] += ev * (float)v[7];
      }
      *(f32x4*)&credv[sg][kb * 8]     = a0;
      *(f32x4*)&credv[sg][kb * 8 + 4] = a1;
    }
    __syncthreads();
    if (tid < 64){
      float inv = 1.0f / ((sred[0] + sred[1]) + (sred[2] + sred[3]));
      int k2 = tid * 2;
      float c0 = 0.f, c1 = 0.f;
      #pragma unroll
      for (int r = 0; r < 16; r++){
        float2 p = *(const float2*)&credv[r][k2];
        c0 += p.x; c1 += p.y;
      }
      c0 *= inv; c1 *= inv;
      st4v((unsigned*)(hctx + ((size_t)t * 16 + bB) * 1536 + 512 + sQ * 128 + k2),
           pack2(f2bf(c0), f2bf(c1)));
    }
    gridbar3(arr, 2 * t + 1);

    // ====== phase D: stage ctx; ctx@Wc + g1l -> gates -> cell ======
    #pragma unroll
    for (int r = 0; r < 8; r++){
      int u = tid + r * 256;
      int b = u >> 7, s16 = u & 127;
      const us* s = hctx + ((size_t)t * 16 + b) * 1536 + 512 + s16 * 8;
      ull lo = ld8v(s), hi = ld8v(s + 4);
      *(ull*)&Xrow[b][s16 * 8]     = lo;
      *(ull*)&Xrow[b][s16 * 8 + 4] = hi;
    }
    __syncthreads();
    {
      f32x4 acc = {};
      #pragma unroll
      for (int m = 0; m < 8; m++){
        int ks = wv * 8 + m;
        int ch = lane >> 4, b = lane & 15;
        acc = __builtin_amdgcn_mfma_f32_16x16x32_bf16(*(const bf16x8*)&Xrow[b][ks * 32 + ch * 8],
                                                      *(const bf16x8*)Wc[(ks * 4 + ch) * 16 + b],
                                                      acc, 0, 0, 0);
      }
      P[wv][lane] = acc;
    }
    __syncthreads();
    if (wv == 0){
      f32x4 sum = (P[0][lane] + P[1][lane]) + (P[2][lane] + P[3][lane]);
      int v = lane & 15;
      #pragma unroll
      for (int r = 0; r < 4; r++){
        int b = (lane >> 4) * 4 + r;
        gl[v][b] = sum[r] + g1l[v][b];
      }
    }
    __syncthreads();
    if (tid < 64){
      int b2 = tid & 15, joff = tid >> 4;
      float ig = sigm (gl[joff * 4 + 0][b2]);
      float fg = sigm (gl[joff * 4 + 1][b2]);
      float g2 = tanhf(gl[joff * 4 + 2][b2]);
      float og = sigm (gl[joff * 4 + 3][b2]);
      float cn = fg * creg + ig * g2;
      float hv = og * tanhf(cn);
      creg = cn;
      hvs[b2][joff] = hv;
    }
    __syncthreads();
    if (tid < 32){
      int b = tid & 15, jp = tid >> 4;
      st4v((unsigned*)(hctx + ((size_t)t * 16 + b) * 1536 + bx * 4 + jp * 2),
           pack2(f2bf(hvs[b][jp * 2]), f2bf(hvs[b][jp * 2 + 1])));
    }
    gridbar3(arr, 2 * t + 2);
    if (bx == 0 && tid == 0)
      __hip_atomic_store(tdone, (unsigned)(t + 1), __ATOMIC_RELEASE, __HIP_MEMORY_SCOPE_AGENT);
  }
}

extern "C" void kernel_launch(void* const* d_in, const int* in_sizes, int n_in,
                              void* d_out, int out_size, void* d_ws, size_t ws_size,
                              hipStream_t stream)
{
  const int*   src       = (const int*)d_in[0];
  const int*   src_lens  = (const int*)d_in[1];
  const int*   tgt       = (const int*)d_in[2];
  const float* enc_embed = (const float*)d_in[3];
  const float* Wih_f = (const float*)d_in[4];
  const float* Whh_f = (const float*)d_in[5];
  const float* bih_f = (const float*)d_in[6];
  const float* bhh_f = (const float*)d_in[7];
  const float* Wih_b = (const float*)d_in[8];
  const float* Whh_b = (const float*)d_in[9];
  const float* bih_b = (const float*)d_in[10];
  const float* bhh_b = (const float*)d_in[11];
  const float* Wbh = (const float*)d_in[12];
  const float* bbh = (const float*)d_in[13];
  const float* Wbc = (const float*)d_in[14];
  const float* bbc = (const float*)d_in[15];
  const float* Wh_att = (const float*)d_in[16];
  const float* Ws_att = (const float*)d_in[17];
  const float* v_att  = (const float*)d_in[18];
  const float* dec_embed = (const float*)d_in[19];
  const float* Wih_d = (const float*)d_in[20];
  const float* Whh_d = (const float*)d_in[21];
  const float* bih_d = (const float*)d_in[22];
  const float* bhh_d = (const float*)d_in[23];
  const float* Wfc = (const float*)d_in[24];
  const float* bfc = (const float*)d_in[25];
  float* out = (float*)d_out;

  char* base = (char*)d_ws;
  size_t off = 0;
  auto take = [&](size_t bytes) -> char* {
    char* p = base + off;
    off += (bytes + 255) & ~(size_t)255;
    return p;
  };
  us* wfc_bf    = (us*)take((size_t)32000 * 1536 * 2);
  us* emb_e     = (us*)take((size_t)2048 * 512 * 2);
  us* emb_d     = (us*)take((size_t)2048 * 512 * 2);
  us* wihf_bf   = (us*)take((size_t)2048 * 512 * 2);
  us* wihb_bf   = (us*)take((size_t)2048 * 512 * 2);
  us* wihd_bf   = (us*)take((size_t)2048 * 1536 * 2);
  us* whhf_bf   = (us*)take((size_t)2048 * 512 * 2);
  us* whhb_bf   = (us*)take((size_t)2048 * 512 * 2);
  us* whhd_bf   = (us*)take((size_t)2048 * 512 * 2);
  us* whatt_bf  = (us*)take((size_t)512 * 1024 * 2);
  float* gin_f    = (float*)take((size_t)2048 * 2048 * 4);
  float* gin_b    = (float*)take((size_t)2048 * 2048 * 4);
  float* gin_d    = (float*)take((size_t)2048 * 2048 * 4);
  us* enc_out_bf  = (us*)take((size_t)2048 * 1024 * 2);
  us* enc_proj_bf = (us*)take((size_t)2048 * 512 * 2);
  us* hctx        = (us*)take((size_t)2048 * 1536 * 2);
  us* h0_bf       = (us*)take((size_t)16 * 512 * 2);
  float* c_dec    = (float*)take((size_t)16 * 512 * 4);
  float* pscore_g = (float*)take((size_t)16 * 1024 * 4);
  float* bias_f = (float*)take(2048 * 4);
  float* bias_b = (float*)take(2048 * 4);
  float* bias_d = (float*)take(2048 * 4);
  unsigned* arrF  = (unsigned*)take(64 * 16 * 4);
  unsigned* arrB  = (unsigned*)take(64 * 16 * 4);
  unsigned* arrD  = (unsigned*)take(128 * 16 * 4);
  unsigned* arrG  = (unsigned*)take(16 * 8 * 16 * 4);
  unsigned* tdone = (unsigned*)take(256);

  // zeroing: padded dec-embedding rows, hctx, barrier flags + t_done
  hipMemsetAsync(emb_d, 0, (size_t)2048 * 512 * 2, stream);
  hipMemsetAsync(hctx, 0, (size_t)2048 * 1536 * 2, stream);
  hipMemsetAsync(arrF, 0, (64 * 16 + 64 * 16 + 128 * 16 + 16 * 8 * 16) * 4 + 256, stream);

  // weight conversions
  k_f2bf<<<4096, 256, 0, stream>>>((const float4*)Wfc,   (uint2*)wfc_bf,   (long)32000 * 1536 / 4);
  k_f2bf<<<512,  256, 0, stream>>>((const float4*)Wih_f, (uint2*)wihf_bf,  (long)2048 * 512 / 4);
  k_f2bf<<<512,  256, 0, stream>>>((const float4*)Wih_b, (uint2*)wihb_bf,  (long)2048 * 512 / 4);
  k_f2bf<<<1024, 256, 0, stream>>>((const float4*)Wih_d, (uint2*)wihd_bf,  (long)2048 * 1536 / 4);
  k_f2bf<<<512,  256, 0, stream>>>((const float4*)Whh_f, (uint2*)whhf_bf,  (long)2048 * 512 / 4);
  k_f2bf<<<512,  256, 0, stream>>>((const float4*)Whh_b, (uint2*)whhb_bf,  (long)2048 * 512 / 4);
  k_f2bf<<<512,  256, 0, stream>>>((const float4*)Whh_d, (uint2*)whhd_bf,  (long)2048 * 512 / 4);
  k_f2bf<<<512,  256, 0, stream>>>((const float4*)Wh_att,(uint2*)whatt_bf, (long)512 * 1024 / 4);
  k_bias3<<<8, 256, 0, stream>>>(bih_f, bhh_f, bias_f, bih_b, bhh_b, bias_b, bih_d, bhh_d, bias_d);

  // embeddings (bf16), rows r = pos*16 + b
  k_embed<<<2048, 128, 0, stream>>>(src, enc_embed, emb_e);
  k_embed<<<2032, 128, 0, stream>>>(tgt, dec_embed, emb_d);

  // input-side gate GEMMs (hoisted out of the scans)
  gemm_bt<0><<<dim3(16, 16), 256, 0, stream>>>(emb_e, 512, wihf_bf, 512,  bias_f, gin_f, 2048, 512, 4096);
  gemm_bt<0><<<dim3(16, 16), 256, 0, stream>>>(emb_e, 512, wihb_bf, 512,  bias_b, gin_b, 2048, 512, 4096);
  gemm_bt<0><<<dim3(16, 16), 256, 0, stream>>>(emb_d, 512, wihd_bf, 1536, bias_d, gin_d, 2048, 512, 4096);

  // encoder: persistent, independent fwd/bwd 64-block barrier domains
  enc_persist5<<<128, 256, 0, stream>>>(gin_f, gin_b, whhf_bf, whhb_bf, enc_out_bf, arrF, arrB);

  k_h0c0<<<32, 512, 0, stream>>>(enc_out_bf, Wbh, bbh, Wbc, bbc, h0_bf, c_dec);

  // enc_proj (bf16) = enc_out @ Wh_att^T
  gemm_bt<2><<<dim3(4, 16), 256, 0, stream>>>(enc_out_bf, 1024, whatt_bf, 1024, nullptr, enc_proj_bf, 512, 1024, 4096);

  // fused decoder v10 + streaming logits GEMM (128 producers + 128 consumers)
  dec_fused5<<<256, 256, 0, stream>>>(h0_bf, c_dec, Ws_att, v_att, enc_proj_bf, enc_out_bf, src_lens,
                                      gin_d, whhd_bf, wihd_bf, pscore_g, hctx,
                                      wfc_bf, bfc, out, arrD, arrG, tdone);
}